// Round 9
// baseline (2296.147 us; speedup 1.0000x reference)
//
#include <hip/hip_runtime.h>

#define B_ 4
#define T_ 4096
#define D_ 2048
#define H_ 16
#define DK_ 64
#define DV_ 128
#define HDK 1024
#define HDV 2048
#define NN 3072
#define MM 16384
#define KT_ 64  // D_/32 K-tiles (BK=32)

typedef unsigned short u16;
typedef unsigned int u32;
typedef __attribute__((ext_vector_type(8))) short bf16x8;
typedef __attribute__((ext_vector_type(4))) float f32x4;

typedef const __attribute__((address_space(1))) u16 gu16;
typedef __attribute__((address_space(3))) u16 lu16;

__device__ __forceinline__ float b2f(u16 u) {
  u32 x = ((u32)u) << 16; float f; __builtin_memcpy(&f, &x, 4); return f;
}
__device__ __forceinline__ u16 f2b(float f) {
  u32 x; __builtin_memcpy(&x, &f, 4);
  u32 r = x + 0x7FFFu + ((x >> 16) & 1u);
  return (u16)(r >> 16);
}
// fast logsig / exp via native v_exp_f32 / v_log_f32
__device__ __forceinline__ float fexp(float x) { return exp2f(x * 1.44269504f); }
__device__ __forceinline__ float flogsig(float z) {
  float u = exp2f(-fabsf(z) * 1.44269504f);
  float l = log2f(1.f + u) * 0.69314718f;
  return fminf(z, 0.f) - l;
}

// K1: convert [k_w; v_w] (3072 x 2048 f32) -> bf16
__global__ __launch_bounds__(256) void k_cvtw(const float* __restrict__ kw,
                                              const float* __restrict__ vw,
                                              u16* __restrict__ Wb) {
  int i = blockIdx.x * 256 + threadIdx.x;
  size_t e = (size_t)i * 8;
  const float* src = (e < (size_t)HDK * D_) ? (kw + e) : (vw + (e - (size_t)HDK * D_));
  float4 f0 = ((const float4*)src)[0];
  float4 f1 = ((const float4*)src)[1];
  union { int4 v; u16 u[8]; } o;
  o.u[0] = f2b(f0.x); o.u[1] = f2b(f0.y); o.u[2] = f2b(f0.z); o.u[3] = f2b(f0.w);
  o.u[4] = f2b(f1.x); o.u[5] = f2b(f1.y); o.u[6] = f2b(f1.z); o.u[7] = f2b(f1.w);
  *(int4*)(Wb + e) = o.v;
}

// K2: RMSNorm -> x (bf16), y = x @ gk_w1^T. Reduction: 2 butterfly levels over
// ALL 64 values (4-group pre-sums), THEN shard j-sets by a=ln&3 and butterfly
// o in {4,8,16,32}. Each residue class has one lane per 4-group, so the
// sharded sum covers all 64 lanes (this is the fix of R4's bug, which
// skipped the pre-reduction). 192 shfls vs 384.
__global__ __launch_bounds__(256) void k_rms(const float* __restrict__ hs,
                                             const float* __restrict__ nw,
                                             const float* __restrict__ w1,
                                             u16* __restrict__ xb,
                                             float* __restrict__ y) {
  int r0 = blockIdx.x * 4;
  int tid = threadIdx.x;
  int wv = tid >> 6, ln = tid & 63;
  __shared__ float red[4][4];
  __shared__ float ys2[4][4][4][4];  // [wv][r][a][jj]
  float x[4][8];
  float ssq[4];
  #pragma unroll
  for (int r = 0; r < 4; ++r) {
    const float4* hp = (const float4*)(hs + (size_t)(r0 + r) * D_);
    float4 a = hp[tid * 2], b = hp[tid * 2 + 1];
    x[r][0] = a.x; x[r][1] = a.y; x[r][2] = a.z; x[r][3] = a.w;
    x[r][4] = b.x; x[r][5] = b.y; x[r][6] = b.z; x[r][7] = b.w;
    float s = 0.f;
    #pragma unroll
    for (int i = 0; i < 8; ++i) s += x[r][i] * x[r][i];
    #pragma unroll
    for (int o = 32; o > 0; o >>= 1) s += __shfl_xor(s, o, 64);
    ssq[r] = s;
  }
  if (ln == 0) {
    #pragma unroll
    for (int r = 0; r < 4; ++r) red[wv][r] = ssq[r];
  }
  __syncthreads();
  const float4* np_ = (const float4*)nw;
  float4 n0 = np_[tid * 2], n1 = np_[tid * 2 + 1];
  float nwv[8] = {n0.x, n0.y, n0.z, n0.w, n1.x, n1.y, n1.z, n1.w};
  #pragma unroll
  for (int r = 0; r < 4; ++r) {
    float tot = red[0][r] + red[1][r] + red[2][r] + red[3][r];
    float inv = rsqrtf(tot * (1.f / D_) + 1e-5f);
    union { int4 v; u16 u[8]; } o;
    #pragma unroll
    for (int i = 0; i < 8; ++i) { x[r][i] = x[r][i] * inv * nwv[i]; o.u[i] = f2b(x[r][i]); }
    *(int4*)(xb + (size_t)(r0 + r) * D_ + tid * 8) = o.v;
  }
  float p[4][16];
  #pragma unroll
  for (int j = 0; j < 16; ++j) {
    const float4* wp = (const float4*)(w1 + (size_t)j * D_);
    float4 a = wp[tid * 2], b = wp[tid * 2 + 1];
    float wj[8] = {a.x, a.y, a.z, a.w, b.x, b.y, b.z, b.w};
    #pragma unroll
    for (int r = 0; r < 4; ++r) {
      float s = 0.f;
      #pragma unroll
      for (int i = 0; i < 8; ++i) s += x[r][i] * wj[i];
      p[r][j] = s;
    }
  }
  // levels 1,2 over all 64 values -> 4-group sums (replicated in group)
  #pragma unroll
  for (int r = 0; r < 4; ++r)
    #pragma unroll
    for (int j = 0; j < 16; ++j) {
      p[r][j] += __shfl_xor(p[r][j], 1, 64);
      p[r][j] += __shfl_xor(p[r][j], 2, 64);
    }
  // shard: lane keeps j-set a = ln&3 (static cndmask select, no dyn index)
  int a = ln & 3;
  float q[4][4];
  #pragma unroll
  for (int r = 0; r < 4; ++r)
    #pragma unroll
    for (int jj = 0; jj < 4; ++jj) {
      float lo = (a & 1) ? p[r][4 + jj] : p[r][jj];
      float hi = (a & 1) ? p[r][12 + jj] : p[r][8 + jj];
      q[r][jj] = (a & 2) ? hi : lo;
    }
  #pragma unroll
  for (int o = 4; o <= 32; o <<= 1)
    #pragma unroll
    for (int r = 0; r < 4; ++r)
      #pragma unroll
      for (int jj = 0; jj < 4; ++jj)
        q[r][jj] += __shfl_xor(q[r][jj], o, 64);
  if (ln < 4) {
    #pragma unroll
    for (int r = 0; r < 4; ++r)
      #pragma unroll
      for (int jj = 0; jj < 4; ++jj)
        ys2[wv][r][ln][jj] = q[r][jj];
  }
  __syncthreads();
  if (tid < 64) {
    int r = tid >> 4, j = tid & 15;
    float s = 0.f;
    #pragma unroll
    for (int w = 0; w < 4; ++w) s += ys2[w][r][j >> 2][j & 3];
    y[(size_t)(r0 + r) * 16 + j] = s;
  }
}

// K3: kv = x @ Wb^T. 256x256 tile, 8 waves, BK=32, 2-slot dbuf = 64KB LDS
// -> 2 blocks/CU (4 waves/SIMD). Staging map R7/R8-proven: wave-uniform GLDS
// dest (wave w rows w*32..+31, lane l -> row l>>2, col (l&3)*8, source col
// pre-swizzled by (l>>3)&3), read kcol = 8*(kq^((r>>1)&3)) (PMC=0 verified).
// Counted vmcnt(4) in-loop; cross-block overlap hides the barrier drain.
#define GLDS(SRC, DST) __builtin_amdgcn_global_load_lds((gu16*)(SRC), (lu16*)(DST), 16, 0, 0)

#define KITER(DB, NB, KTN, VMSTR, ST) do {                                     \
    if (ST) {                                                                  \
      const u16* An = Ag + (size_t)(KTN) * 32;                                 \
      const u16* Bn = Bg + (size_t)(KTN) * 32;                                 \
      GLDS(An, &SA[NB][lw]); GLDS(An + 16 * D_, &SA[NB][lw + 512]);            \
      GLDS(Bn, &SB[NB][lw]); GLDS(Bn + 16 * D_, &SB[NB][lw + 512]);            \
    }                                                                          \
    asm volatile("s_waitcnt vmcnt(" VMSTR ")" ::: "memory");                   \
    __builtin_amdgcn_s_barrier();                                              \
    __builtin_amdgcn_sched_barrier(0);                                         \
    bf16x8 bfr[4];                                                             \
    _Pragma("unroll")                                                          \
    for (int ni = 0; ni < 4; ++ni)                                             \
      bfr[ni] = *(const bf16x8*)&SB[DB][(wc * 64 + ni * 16 + r) * 32 + kcol];  \
    bf16x8 afr[8];                                                             \
    _Pragma("unroll")                                                          \
    for (int mi = 0; mi < 8; ++mi)                                             \
      afr[mi] = *(const bf16x8*)&SA[DB][(wr * 128 + mi * 16 + r) * 32 + kcol]; \
    asm volatile("s_waitcnt lgkmcnt(0)" ::: "memory");                         \
    __builtin_amdgcn_sched_barrier(0);                                         \
    __builtin_amdgcn_s_setprio(1);                                             \
    _Pragma("unroll")                                                          \
    for (int mi = 0; mi < 8; ++mi)                                             \
      _Pragma("unroll")                                                        \
      for (int ni = 0; ni < 4; ++ni)                                           \
        acc[mi][ni] = __builtin_amdgcn_mfma_f32_16x16x32_bf16(afr[mi], bfr[ni], acc[mi][ni], 0, 0, 0); \
    __builtin_amdgcn_s_setprio(0);                                             \
    __builtin_amdgcn_s_barrier();                                              \
  } while (0)

__global__ __launch_bounds__(512, 4) void k_gemm(const u16* __restrict__ X,
                                                 const u16* __restrict__ W,
                                                 u16* __restrict__ C) {
  __shared__ u16 SA[2][8192];  // [dbuf][256 rows x 32 cols] = 32KB
  __shared__ u16 SB[2][8192];  // 32KB  -> total 64KB -> 2 blocks/CU
  int bid = blockIdx.x;
  int swzb = (bid & 7) * 96 + (bid >> 3);   // bijective XCD swizzle (768%8==0)
  int tm = swzb / 12, tn = swzb - tm * 12;
  int m0 = tm << 8, n0 = tn << 8;
  int tid = threadIdx.x;
  int w = tid >> 6, l = tid & 63;
  int wr = w >> 2, wc = w & 3;
  // staging coords (wave-uniform LDS base; per-lane global src)
  int arow = w * 32 + (l >> 2);
  int csw = 8 * ((l & 3) ^ ((l >> 3) & 3));   // pre-swizzled source col
  const u16* Ag = X + (size_t)(m0 + arow) * D_ + csw;
  const u16* Bg = W + (size_t)(n0 + arow) * D_ + csw;
  int lw = w * 1024;                           // u16 offset of wave's chunk pair
  // fragment read coords
  int r = l & 15, kq = l >> 4;
  int kcol = 8 * (kq ^ ((r >> 1) & 3));

  f32x4 acc[8][4];
  #pragma unroll
  for (int mi = 0; mi < 8; ++mi)
    #pragma unroll
    for (int ni = 0; ni < 4; ++ni)
      #pragma unroll
      for (int q = 0; q < 4; ++q) acc[mi][ni][q] = 0.f;

  // prologue: tile 0 into slot 0
  GLDS(Ag, &SA[0][lw]); GLDS(Ag + 16 * D_, &SA[0][lw + 512]);
  GLDS(Bg, &SB[0][lw]); GLDS(Bg + 16 * D_, &SB[0][lw + 512]);

  for (int kt = 0; kt < KT_ - 1; ++kt) {
    int db = kt & 1, nb = db ^ 1;
    KITER(db, nb, kt + 1, "4", 1);
  }
  KITER(1, 0, 0, "0", 0);

  int cr = (l >> 4) * 4, cc = l & 15;
  #pragma unroll
  for (int mi = 0; mi < 8; ++mi)
    #pragma unroll
    for (int ni = 0; ni < 4; ++ni)
      #pragma unroll
      for (int q = 0; q < 4; ++q) {
        int gm = m0 + wr * 128 + mi * 16 + cr + q;
        int gn = n0 + wc * 64 + ni * 16 + cc;
        C[(size_t)gm * NN + gn] = f2b(acc[mi][ni][q]);
      }
}

// K4: fused gk + chunk-sum, 64-t chunks, grid 1024. gk stored f16;
// ct accumulated from the f16-ROUNDED values (bit-consistent with k_decay).
__global__ __launch_bounds__(256) void k_gkcs(const float* __restrict__ y,
                                              const float* __restrict__ w2,
                                              const float* __restrict__ gb,
                                              u16* __restrict__ gkh,
                                              float* __restrict__ ct) {
  __shared__ float yl[64][16];
  int blk = blockIdx.x;
  int cg = blk & 3, tc = (blk >> 2) & 63, b = blk >> 8;
  int tid = threadIdx.x;
  int c = cg * 256 + tid;
  {
    int row = tid >> 2, q = tid & 3;
    const float4* src = (const float4*)(y + (size_t)(b * T_ + tc * 64 + row) * 16 + q * 4);
    *(float4*)&yl[row][q * 4] = *src;
  }
  float w2r[16];
  {
    const float4* wsrc = (const float4*)(w2 + (size_t)c * 16);
    float4 q0 = wsrc[0], q1 = wsrc[1], q2 = wsrc[2], q3 = wsrc[3];
    w2r[0] = q0.x; w2r[1] = q0.y; w2r[2] = q0.z; w2r[3] = q0.w;
    w2r[4] = q1.x; w2r[5] = q1.y; w2r[6] = q1.z; w2r[7] = q1.w;
    w2r[8] = q2.x; w2r[9] = q2.y; w2r[10] = q2.z; w2r[11] = q2.w;
    w2r[12] = q3.x; w2r[13] = q3.y; w2r[14] = q3.z; w2r[15] = q3.w;
  }
  float gbr = gb[c];
  __syncthreads();
  float sum = 0.f;
  size_t rowbase = (size_t)(b * T_ + tc * 64) * HDK + c;
  for (int t = 0; t < 64; ++t) {
    const float4* yv4 = (const float4*)&yl[t][0];
    float4 y0 = yv4[0], y1 = yv4[1], y2 = yv4[2], y3 = yv4[3];
    float z = gbr;
    z = fmaf(y0.x, w2r[0], z);  z = fmaf(y0.y, w2r[1], z);
    z = fmaf(y0.z, w2r[2], z);  z = fmaf(y0.w, w2r[3], z);
    z = fmaf(y1.x, w2r[4], z);  z = fmaf(y1.y, w2r[5], z);
    z = fmaf(y1.z, w2r[6], z);  z = fmaf(y1.w, w2r[7], z);
    z = fmaf(y2.x, w2r[8], z);  z = fmaf(y2.y, w2r[9], z);
    z = fmaf(y2.z, w2r[10], z); z = fmaf(y2.w, w2r[11], z);
    z = fmaf(y3.x, w2r[12], z); z = fmaf(y3.y, w2r[13], z);
    z = fmaf(y3.z, w2r[14], z); z = fmaf(y3.w, w2r[15], z);
    float g = flogsig(z) * (1.f / 16.f);
    _Float16 hv = (_Float16)g;
    u16 bits; __builtin_memcpy(&bits, &hv, 2);
    gkh[rowbase + (size_t)t * HDK] = bits;
    sum += (float)hv;
  }
  ct[(size_t)(b * 64 + tc) * HDK + c] = sum;
}

// E2: scan 64 chunk sums -> exclusive offsets + totals. grid 16 (b x cg).
__global__ __launch_bounds__(256) void k_scan(const float* __restrict__ ct,
                                              float* __restrict__ co,
                                              float* __restrict__ gt) {
  int b = blockIdx.x >> 2, cg = blockIdx.x & 3;
  int c = cg * 256 + threadIdx.x;
  float run = 0.f;
  #pragma unroll 8
  for (int tc = 0; tc < 64; ++tc) {
    size_t idx = (size_t)(b * 64 + tc) * HDK + c;
    co[idx] = run;
    run += ct[idx];
  }
  gt[b * HDK + c] = run;
}

// E3: A = k * exp(g_total - G) (bf16). 64-t chunks, grid 1024.
__global__ __launch_bounds__(256) void k_decay(const u16* __restrict__ gkh,
                                               const float* __restrict__ co,
                                               const float* __restrict__ gt,
                                               const u16* __restrict__ kv,
                                               u16* __restrict__ Ab) {
  int blk = blockIdx.x;
  int cg = blk & 3, tc = (blk >> 2) & 63, b = blk >> 8;
  int c = cg * 256 + threadIdx.x;
  float run = co[(size_t)(b * 64 + tc) * HDK + c];
  float g = gt[b * HDK + c];
  #pragma unroll 8
  for (int tt = 0; tt < 64; ++tt) {
    size_t row = (size_t)(b * T_) + tc * 64 + tt;
    u16 bits = gkh[row * HDK + c];
    _Float16 hv; __builtin_memcpy(&hv, &bits, 2);
    run += (float)hv;
    float decay = fexp(g - run);
    float kvl = b2f(kv[row * NN + c]);
    Ab[row * HDK + c] = f2b(kvl * decay);
  }
}

// K6: MFMA outer product. block = (s, h, b); 8 splits x 512 t; K-steps of 32 t.
__global__ __launch_bounds__(256) void k_outer(const u16* __restrict__ Ab,
                                               const u16* __restrict__ kv,
                                               float* __restrict__ part) {
  __shared__ u16 At[2][64][40];
  __shared__ u16 Vt[2][128][40];
  int s = blockIdx.x, h = blockIdx.y, b = blockIdx.z;
  int tid = threadIdx.x;
  int w = tid >> 6, l = tid & 63;
  int adk = tid & 63, atq = tid >> 6;
  int vdv = tid & 127, vth = tid >> 7;
  int r = l & 15, q = l >> 4;
  f32x4 acc[8];
  #pragma unroll
  for (int n = 0; n < 8; ++n)
    #pragma unroll
    for (int j = 0; j < 4; ++j) acc[n][j] = 0.f;

  union { int4 v[2]; u16 u[16]; } vbuf;
  union { int4 v; u16 u[8]; } abuf;

  #define LOADT(KK) do {                                                              \
      int t0_ = s * 512 + (KK) * 32;                                                  \
      _Pragma("unroll")                                                               \
      for (int i = 0; i < 8; ++i)                                                     \
        abuf.u[i] = Ab[(size_t)(b * T_ + t0_ + atq * 8 + i) * HDK + h * DK_ + adk];   \
      _Pragma("unroll")                                                               \
      for (int i = 0; i < 16; ++i)                                                    \
        vbuf.u[i] = kv[(size_t)(b * T_ + t0_ + vth * 16 + i) * NN + HDK + h * DV_ + vdv]; \
    } while (0)

  #define WRITET(BF) do {                                                             \
      *(int4*)&At[BF][adk][atq * 8] = abuf.v;                                         \
      *(int4*)&Vt[BF][vdv][vth * 16] = vbuf.v[0];                                     \
      *(int4*)&Vt[BF][vdv][vth * 16 + 8] = vbuf.v[1];                                 \
    } while (0)

  LOADT(0);
  WRITET(0);
  for (int kk = 0; kk < 16; ++kk) {
    int cur = kk & 1;
    if (kk < 15) LOADT(kk + 1);
    __syncthreads();
    bf16x8 af = *(const bf16x8*)&At[cur][w * 16 + r][q * 8];
    #pragma unroll
    for (int n = 0; n < 8; ++n) {
      bf16x8 vf = *(const bf16x8*)&Vt[cur][n * 16 + r][q * 8];
      acc[n] = __builtin_amdgcn_mfma_f32_16x16x32_bf16(af, vf, acc[n], 0, 0, 0);
    }
    __syncthreads();
    if (kk < 15) WRITET(1 - cur);
  }
  #undef LOADT
  #undef WRITET

  float* dst = part + ((size_t)(b * H_ + h) * 8 + s) * (DK_ * DV_);
  #pragma unroll
  for (int n = 0; n < 8; ++n)
    #pragma unroll
    for (int j = 0; j < 4; ++j)
      dst[(w * 16 + q * 4 + j) * DV_ + n * 16 + r] = acc[n][j];
}

// K7: out = exp(g_total)*state + sum over 8 splits
__global__ __launch_bounds__(256) void k_final(const float* __restrict__ part,
                                               const float* __restrict__ gt,
                                               const float* __restrict__ st,
                                               float* __restrict__ out) {
  int i = blockIdx.x * 256 + threadIdx.x;
  int dv = i & 127, dk = (i >> 7) & 63, h = (i >> 13) & 15, b = i >> 17;
  size_t base = ((size_t)(b * H_ + h) * 8) * 8192 + dk * DV_ + dv;
  float s = 0.f;
  #pragma unroll
  for (int sp = 0; sp < 8; ++sp) s += part[base + (size_t)sp * 8192];
  float g = gt[b * HDK + h * DK_ + dk];
  out[i] = fexp(g) * st[i] + s;
}

extern "C" void kernel_launch(void* const* d_in, const int* in_sizes, int n_in,
                              void* d_out, int out_size, void* d_ws, size_t ws_size,
                              hipStream_t stream) {
  const float* hs = (const float*)d_in[0];
  const float* st = (const float*)d_in[1];
  const float* nw = (const float*)d_in[2];
  const float* kw = (const float*)d_in[3];
  const float* vw = (const float*)d_in[4];
  const float* w1 = (const float*)d_in[5];
  const float* w2 = (const float*)d_in[6];
  const float* gb = (const float*)d_in[7];
  float* out = (float*)d_out;
  char* ws = (char*)d_ws;

  u16*  Wb  = (u16*)(ws + 0);              // 12,582,912
  u16*  xb  = (u16*)(ws + 12582912);       // 67,108,864 (dead after gemm)
  float* y  = (float*)(ws + 79691776);     //  1,048,576
  u16*  kv  = (u16*)(ws + 80740352);       // 100,663,296
  u16*  gkh = (u16*)(ws + 181403648);      // 33,554,432 (f16)
  float* ct = (float*)(ws + 214958080);    //  1,048,576
  float* co = (float*)(ws + 216006656);    //  1,048,576
  float* gt = (float*)(ws + 217055232);    //     16,384
  u16*  Ab  = (u16*)(ws + 12582912);              // reuse xb region (33.5 MB)
  float* part = (float*)(ws + 12582912 + 33554432); // 16,777,216

  k_cvtw<<<dim3(3072), dim3(256), 0, stream>>>(kw, vw, Wb);
  k_rms<<<dim3(4096), dim3(256), 0, stream>>>(hs, nw, w1, xb, y);
  k_gemm<<<dim3(768), dim3(512), 0, stream>>>(xb, Wb, kv);
  k_gkcs<<<dim3(1024), dim3(256), 0, stream>>>(y, w2, gb, gkh, ct);
  k_scan<<<dim3(16), dim3(256), 0, stream>>>(ct, co, gt);
  k_decay<<<dim3(1024), dim3(256), 0, stream>>>(gkh, co, gt, kv, Ab);
  k_outer<<<dim3(8, 16, 4), dim3(256), 0, stream>>>(Ab, kv, part);
  k_final<<<dim3(2048), dim3(256), 0, stream>>>(part, gt, st, out);
}

// Round 10
// 425.060 us; speedup vs baseline: 5.4019x; 5.4019x over previous
//
#include <hip/hip_runtime.h>

#define B_ 4
#define T_ 4096
#define D_ 2048
#define H_ 16
#define DK_ 64
#define DV_ 128
#define HDK 1024
#define HDV 2048
#define NN 3072
#define MM 16384
#define KT_ 64  // D_/32 K-tiles

typedef unsigned short u16;
typedef unsigned int u32;
typedef __attribute__((ext_vector_type(8))) short bf16x8;
typedef __attribute__((ext_vector_type(4))) float f32x4;

typedef const __attribute__((address_space(1))) u16 gu16;
typedef __attribute__((address_space(3))) u16 lu16;

__device__ __forceinline__ float b2f(u16 u) {
  u32 x = ((u32)u) << 16; float f; __builtin_memcpy(&f, &x, 4); return f;
}
__device__ __forceinline__ u16 f2b(float f) {
  u32 x; __builtin_memcpy(&x, &f, 4);
  u32 r = x + 0x7FFFu + ((x >> 16) & 1u);
  return (u16)(r >> 16);
}
// fast logsig / exp via native v_exp_f32 / v_log_f32
__device__ __forceinline__ float fexp(float x) { return exp2f(x * 1.44269504f); }
__device__ __forceinline__ float flogsig(float z) {
  float u = exp2f(-fabsf(z) * 1.44269504f);
  float l = log2f(1.f + u) * 0.69314718f;
  return fminf(z, 0.f) - l;
}

// K1: convert [k_w; v_w] (3072 x 2048 f32) -> bf16
__global__ __launch_bounds__(256) void k_cvtw(const float* __restrict__ kw,
                                              const float* __restrict__ vw,
                                              u16* __restrict__ Wb) {
  int i = blockIdx.x * 256 + threadIdx.x;
  size_t e = (size_t)i * 8;
  const float* src = (e < (size_t)HDK * D_) ? (kw + e) : (vw + (e - (size_t)HDK * D_));
  float4 f0 = ((const float4*)src)[0];
  float4 f1 = ((const float4*)src)[1];
  union { int4 v; u16 u[8]; } o;
  o.u[0] = f2b(f0.x); o.u[1] = f2b(f0.y); o.u[2] = f2b(f0.z); o.u[3] = f2b(f0.w);
  o.u[4] = f2b(f1.x); o.u[5] = f2b(f1.y); o.u[6] = f2b(f1.z); o.u[7] = f2b(f1.w);
  *(int4*)(Wb + e) = o.v;
}

// K2: RMSNorm -> x (bf16), y = x @ gk_w1^T. (R9-validated: 2 butterfly levels
// over all 64 lanes -> 4-group pre-sums, then shard j-sets by ln&3 and
// butterfly o in {4,8,16,32}; covers all 64 lanes.)
__global__ __launch_bounds__(256) void k_rms(const float* __restrict__ hs,
                                             const float* __restrict__ nw,
                                             const float* __restrict__ w1,
                                             u16* __restrict__ xb,
                                             float* __restrict__ y) {
  int r0 = blockIdx.x * 4;
  int tid = threadIdx.x;
  int wv = tid >> 6, ln = tid & 63;
  __shared__ float red[4][4];
  __shared__ float ys2[4][4][4][4];  // [wv][r][a][jj]
  float x[4][8];
  float ssq[4];
  #pragma unroll
  for (int r = 0; r < 4; ++r) {
    const float4* hp = (const float4*)(hs + (size_t)(r0 + r) * D_);
    float4 a = hp[tid * 2], b = hp[tid * 2 + 1];
    x[r][0] = a.x; x[r][1] = a.y; x[r][2] = a.z; x[r][3] = a.w;
    x[r][4] = b.x; x[r][5] = b.y; x[r][6] = b.z; x[r][7] = b.w;
    float s = 0.f;
    #pragma unroll
    for (int i = 0; i < 8; ++i) s += x[r][i] * x[r][i];
    #pragma unroll
    for (int o = 32; o > 0; o >>= 1) s += __shfl_xor(s, o, 64);
    ssq[r] = s;
  }
  if (ln == 0) {
    #pragma unroll
    for (int r = 0; r < 4; ++r) red[wv][r] = ssq[r];
  }
  __syncthreads();
  const float4* np_ = (const float4*)nw;
  float4 n0 = np_[tid * 2], n1 = np_[tid * 2 + 1];
  float nwv[8] = {n0.x, n0.y, n0.z, n0.w, n1.x, n1.y, n1.z, n1.w};
  #pragma unroll
  for (int r = 0; r < 4; ++r) {
    float tot = red[0][r] + red[1][r] + red[2][r] + red[3][r];
    float inv = rsqrtf(tot * (1.f / D_) + 1e-5f);
    union { int4 v; u16 u[8]; } o;
    #pragma unroll
    for (int i = 0; i < 8; ++i) { x[r][i] = x[r][i] * inv * nwv[i]; o.u[i] = f2b(x[r][i]); }
    *(int4*)(xb + (size_t)(r0 + r) * D_ + tid * 8) = o.v;
  }
  float p[4][16];
  #pragma unroll
  for (int j = 0; j < 16; ++j) {
    const float4* wp = (const float4*)(w1 + (size_t)j * D_);
    float4 a = wp[tid * 2], b = wp[tid * 2 + 1];
    float wj[8] = {a.x, a.y, a.z, a.w, b.x, b.y, b.z, b.w};
    #pragma unroll
    for (int r = 0; r < 4; ++r) {
      float s = 0.f;
      #pragma unroll
      for (int i = 0; i < 8; ++i) s += x[r][i] * wj[i];
      p[r][j] = s;
    }
  }
  #pragma unroll
  for (int r = 0; r < 4; ++r)
    #pragma unroll
    for (int j = 0; j < 16; ++j) {
      p[r][j] += __shfl_xor(p[r][j], 1, 64);
      p[r][j] += __shfl_xor(p[r][j], 2, 64);
    }
  int a = ln & 3;
  float q[4][4];
  #pragma unroll
  for (int r = 0; r < 4; ++r)
    #pragma unroll
    for (int jj = 0; jj < 4; ++jj) {
      float lo = (a & 1) ? p[r][4 + jj] : p[r][jj];
      float hi = (a & 1) ? p[r][12 + jj] : p[r][8 + jj];
      q[r][jj] = (a & 2) ? hi : lo;
    }
  #pragma unroll
  for (int o = 4; o <= 32; o <<= 1)
    #pragma unroll
    for (int r = 0; r < 4; ++r)
      #pragma unroll
      for (int jj = 0; jj < 4; ++jj)
        q[r][jj] += __shfl_xor(q[r][jj], o, 64);
  if (ln < 4) {
    #pragma unroll
    for (int r = 0; r < 4; ++r)
      #pragma unroll
      for (int jj = 0; jj < 4; ++jj)
        ys2[wv][r][ln][jj] = q[r][jj];
  }
  __syncthreads();
  if (tid < 64) {
    int r = tid >> 4, j = tid & 15;
    float s = 0.f;
    #pragma unroll
    for (int w = 0; w < 4; ++w) s += ys2[w][r][j >> 2][j & 3];
    y[(size_t)(r0 + r) * 16 + j] = s;
  }
}

// K3: kv = x @ Wb^T. R5-proven version verbatim: 256x256 tile, 8 waves,
// BK=32, 4-slot LDS ring, 2-phase interleave, iter-end counted vmcnt(8).
#define STAGE4(GP, LB) do {                                                          \
    __builtin_amdgcn_global_load_lds((gu16*)(GP),             (lu16*)(LB),        16, 0, 0); \
    __builtin_amdgcn_global_load_lds((gu16*)((GP) + 16*2048), (lu16*)((LB)+512),  16, 0, 0); \
    __builtin_amdgcn_global_load_lds((gu16*)((GP) + 32*2048), (lu16*)((LB)+1024), 16, 0, 0); \
    __builtin_amdgcn_global_load_lds((gu16*)((GP) + 48*2048), (lu16*)((LB)+1536), 16, 0, 0); \
  } while (0)

#define GITER2(KTV, VMSTR, DO_STAGE) do {                                            \
    int slot_ = (KTV) & 3;                                                           \
    const u16* Ab_ = &SA[slot_][0];                                                  \
    const u16* Bb_ = &SB[slot_][0];                                                  \
    if (DO_STAGE) {                                                                  \
      const u16* gp_ = gsrc + (size_t)((KTV) + 3) * 32;                              \
      u16* lb_ = lbase + (((KTV) + 3) & 3) * 8192;                                   \
      __builtin_amdgcn_global_load_lds((gu16*)(gp_),             (lu16*)(lb_),       16, 0, 0); \
      __builtin_amdgcn_global_load_lds((gu16*)(gp_ + 16*2048),   (lu16*)(lb_+512),   16, 0, 0); \
    }                                                                                \
    bf16x8 bfr[4];                                                                   \
    _Pragma("unroll")                                                                \
    for (int ni = 0; ni < 4; ++ni)                                                   \
      bfr[ni] = *(const bf16x8*)(Bb_ + (wc * 64 + ni * 16 + r) * 32 + kcol);         \
    {                                                                                \
      bf16x8 a0 = *(const bf16x8*)(Ab_ + (wr * 128 + 0 * 16 + r) * 32 + kcol);       \
      bf16x8 a1 = *(const bf16x8*)(Ab_ + (wr * 128 + 1 * 16 + r) * 32 + kcol);       \
      bf16x8 a2 = *(const bf16x8*)(Ab_ + (wr * 128 + 2 * 16 + r) * 32 + kcol);       \
      bf16x8 a3 = *(const bf16x8*)(Ab_ + (wr * 128 + 3 * 16 + r) * 32 + kcol);       \
      __builtin_amdgcn_s_setprio(1);                                                 \
      _Pragma("unroll")                                                              \
      for (int ni = 0; ni < 4; ++ni) {                                               \
        acc[0][ni] = __builtin_amdgcn_mfma_f32_16x16x32_bf16(a0, bfr[ni], acc[0][ni], 0, 0, 0); \
        acc[1][ni] = __builtin_amdgcn_mfma_f32_16x16x32_bf16(a1, bfr[ni], acc[1][ni], 0, 0, 0); \
      }                                                                              \
      _Pragma("unroll")                                                              \
      for (int ni = 0; ni < 4; ++ni) {                                               \
        acc[2][ni] = __builtin_amdgcn_mfma_f32_16x16x32_bf16(a2, bfr[ni], acc[2][ni], 0, 0, 0); \
        acc[3][ni] = __builtin_amdgcn_mfma_f32_16x16x32_bf16(a3, bfr[ni], acc[3][ni], 0, 0, 0); \
      }                                                                              \
      __builtin_amdgcn_s_setprio(0);                                                 \
    }                                                                                \
    __builtin_amdgcn_s_barrier();                                                    \
    __builtin_amdgcn_sched_barrier(0);                                               \
    if (DO_STAGE) {                                                                  \
      const u16* gp_ = gsrc + (size_t)((KTV) + 3) * 32;                              \
      u16* lb_ = lbase + (((KTV) + 3) & 3) * 8192;                                   \
      __builtin_amdgcn_global_load_lds((gu16*)(gp_ + 32*2048),   (lu16*)(lb_+1024), 16, 0, 0); \
      __builtin_amdgcn_global_load_lds((gu16*)(gp_ + 48*2048),   (lu16*)(lb_+1536), 16, 0, 0); \
    }                                                                                \
    {                                                                                \
      bf16x8 a4 = *(const bf16x8*)(Ab_ + (wr * 128 + 4 * 16 + r) * 32 + kcol);       \
      bf16x8 a5 = *(const bf16x8*)(Ab_ + (wr * 128 + 5 * 16 + r) * 32 + kcol);       \
      bf16x8 a6 = *(const bf16x8*)(Ab_ + (wr * 128 + 6 * 16 + r) * 32 + kcol);       \
      bf16x8 a7 = *(const bf16x8*)(Ab_ + (wr * 128 + 7 * 16 + r) * 32 + kcol);       \
      __builtin_amdgcn_s_setprio(1);                                                 \
      _Pragma("unroll")                                                              \
      for (int ni = 0; ni < 4; ++ni) {                                               \
        acc[4][ni] = __builtin_amdgcn_mfma_f32_16x16x32_bf16(a4, bfr[ni], acc[4][ni], 0, 0, 0); \
        acc[5][ni] = __builtin_amdgcn_mfma_f32_16x16x32_bf16(a5, bfr[ni], acc[5][ni], 0, 0, 0); \
      }                                                                              \
      _Pragma("unroll")                                                              \
      for (int ni = 0; ni < 4; ++ni) {                                               \
        acc[6][ni] = __builtin_amdgcn_mfma_f32_16x16x32_bf16(a6, bfr[ni], acc[6][ni], 0, 0, 0); \
        acc[7][ni] = __builtin_amdgcn_mfma_f32_16x16x32_bf16(a7, bfr[ni], acc[7][ni], 0, 0, 0); \
      }                                                                              \
      __builtin_amdgcn_s_setprio(0);                                                 \
    }                                                                                \
    asm volatile("s_waitcnt vmcnt(" VMSTR ")" ::: "memory");                         \
    __builtin_amdgcn_s_barrier();                                                    \
    __builtin_amdgcn_sched_barrier(0);                                               \
  } while (0)

__global__ __launch_bounds__(512, 2) void k_gemm(const u16* __restrict__ X,
                                                 const u16* __restrict__ W,
                                                 u16* __restrict__ C) {
  __shared__ u16 SA[4][8192];
  __shared__ u16 SB[4][8192];
  int bid = blockIdx.x;
  int swzb = (bid & 7) * 96 + (bid >> 3);
  int tm = swzb / 12, tn = swzb - tm * 12;
  int m0 = tm << 8, n0 = tn << 8;
  int tid = threadIdx.x;
  int w = tid >> 6, l = tid & 63;
  int wr = w >> 2, wc = w & 3;
  int sw = w & 3;
  int srow = sw * 64 + (l >> 2);
  int cx = 8 * ((l & 3) ^ ((l >> 3) & 3));
  const u16* gsrc = ((w < 4) ? (X + (size_t)(m0 + srow) * D_)
                             : (W + (size_t)(n0 + srow) * D_)) + cx;
  u16* lbase = ((w < 4) ? &SA[0][0] : &SB[0][0]) + sw * 2048;
  int r = l & 15, kq = l >> 4;
  int kcol = (kq * 8) ^ (((r >> 1) & 3) << 3);

  f32x4 acc[8][4];
  #pragma unroll
  for (int mi = 0; mi < 8; ++mi)
    #pragma unroll
    for (int ni = 0; ni < 4; ++ni)
      #pragma unroll
      for (int q = 0; q < 4; ++q) acc[mi][ni][q] = 0.f;

  #pragma unroll
  for (int t = 0; t < 3; ++t) {
    const u16* gp_ = gsrc + (size_t)t * 32;
    u16* lb_ = lbase + t * 8192;
    STAGE4(gp_, lb_);
  }
  asm volatile("s_waitcnt vmcnt(8)" ::: "memory");
  __builtin_amdgcn_s_barrier();
  __builtin_amdgcn_sched_barrier(0);

  for (int kt = 0; kt < KT_ - 3; ++kt) GITER2(kt, "8", 1);
  GITER2(KT_ - 3, "4", 0);
  GITER2(KT_ - 2, "0", 0);
  GITER2(KT_ - 1, "0", 0);

  int cr = (l >> 4) * 4, cc = l & 15;
  #pragma unroll
  for (int mi = 0; mi < 8; ++mi)
    #pragma unroll
    for (int ni = 0; ni < 4; ++ni)
      #pragma unroll
      for (int q = 0; q < 4; ++q) {
        int gm = m0 + wr * 128 + mi * 16 + cr + q;
        int gn = n0 + wc * 64 + ni * 16 + cc;
        C[(size_t)gm * NN + gn] = f2b(acc[mi][ni][q]);
      }
}

// K4: fused gk + chunk-sum, 64-t chunks, grid 1024. gk stored f16;
// ct accumulated from the f16-ROUNDED values (bit-consistent with k_decay).
__global__ __launch_bounds__(256) void k_gkcs(const float* __restrict__ y,
                                              const float* __restrict__ w2,
                                              const float* __restrict__ gb,
                                              u16* __restrict__ gkh,
                                              float* __restrict__ ct) {
  __shared__ float yl[64][16];
  int blk = blockIdx.x;
  int cg = blk & 3, tc = (blk >> 2) & 63, b = blk >> 8;
  int tid = threadIdx.x;
  int c = cg * 256 + tid;
  {
    int row = tid >> 2, q = tid & 3;
    const float4* src = (const float4*)(y + (size_t)(b * T_ + tc * 64 + row) * 16 + q * 4);
    *(float4*)&yl[row][q * 4] = *src;
  }
  float w2r[16];
  {
    const float4* wsrc = (const float4*)(w2 + (size_t)c * 16);
    float4 q0 = wsrc[0], q1 = wsrc[1], q2 = wsrc[2], q3 = wsrc[3];
    w2r[0] = q0.x; w2r[1] = q0.y; w2r[2] = q0.z; w2r[3] = q0.w;
    w2r[4] = q1.x; w2r[5] = q1.y; w2r[6] = q1.z; w2r[7] = q1.w;
    w2r[8] = q2.x; w2r[9] = q2.y; w2r[10] = q2.z; w2r[11] = q2.w;
    w2r[12] = q3.x; w2r[13] = q3.y; w2r[14] = q3.z; w2r[15] = q3.w;
  }
  float gbr = gb[c];
  __syncthreads();
  float sum = 0.f;
  size_t rowbase = (size_t)(b * T_ + tc * 64) * HDK + c;
  for (int t = 0; t < 64; ++t) {
    const float4* yv4 = (const float4*)&yl[t][0];
    float4 y0 = yv4[0], y1 = yv4[1], y2 = yv4[2], y3 = yv4[3];
    float z = gbr;
    z = fmaf(y0.x, w2r[0], z);  z = fmaf(y0.y, w2r[1], z);
    z = fmaf(y0.z, w2r[2], z);  z = fmaf(y0.w, w2r[3], z);
    z = fmaf(y1.x, w2r[4], z);  z = fmaf(y1.y, w2r[5], z);
    z = fmaf(y1.z, w2r[6], z);  z = fmaf(y1.w, w2r[7], z);
    z = fmaf(y2.x, w2r[8], z);  z = fmaf(y2.y, w2r[9], z);
    z = fmaf(y2.z, w2r[10], z); z = fmaf(y2.w, w2r[11], z);
    z = fmaf(y3.x, w2r[12], z); z = fmaf(y3.y, w2r[13], z);
    z = fmaf(y3.z, w2r[14], z); z = fmaf(y3.w, w2r[15], z);
    float g = flogsig(z) * (1.f / 16.f);
    _Float16 hv = (_Float16)g;
    u16 bits; __builtin_memcpy(&bits, &hv, 2);
    gkh[rowbase + (size_t)t * HDK] = bits;
    sum += (float)hv;
  }
  ct[(size_t)(b * 64 + tc) * HDK + c] = sum;
}

// E2: scan 64 chunk sums -> exclusive offsets + totals. grid 16 (b x cg).
__global__ __launch_bounds__(256) void k_scan(const float* __restrict__ ct,
                                              float* __restrict__ co,
                                              float* __restrict__ gt) {
  int b = blockIdx.x >> 2, cg = blockIdx.x & 3;
  int c = cg * 256 + threadIdx.x;
  float run = 0.f;
  #pragma unroll 8
  for (int tc = 0; tc < 64; ++tc) {
    size_t idx = (size_t)(b * 64 + tc) * HDK + c;
    co[idx] = run;
    run += ct[idx];
  }
  gt[b * HDK + c] = run;
}

// E3: A = k * exp(g_total - G) (bf16). 64-t chunks, grid 1024.
__global__ __launch_bounds__(256) void k_decay(const u16* __restrict__ gkh,
                                               const float* __restrict__ co,
                                               const float* __restrict__ gt,
                                               const u16* __restrict__ kv,
                                               u16* __restrict__ Ab) {
  int blk = blockIdx.x;
  int cg = blk & 3, tc = (blk >> 2) & 63, b = blk >> 8;
  int c = cg * 256 + threadIdx.x;
  float run = co[(size_t)(b * 64 + tc) * HDK + c];
  float g = gt[b * HDK + c];
  #pragma unroll 8
  for (int tt = 0; tt < 64; ++tt) {
    size_t row = (size_t)(b * T_) + tc * 64 + tt;
    u16 bits = gkh[row * HDK + c];
    _Float16 hv; __builtin_memcpy(&hv, &bits, 2);
    run += (float)hv;
    float decay = fexp(g - run);
    float kvl = b2f(kv[row * NN + c]);
    Ab[row * HDK + c] = f2b(kvl * decay);
  }
}

// K6: MFMA outer product. block = (s, h, b); 8 splits x 512 t; K-steps of 32 t.
__global__ __launch_bounds__(256) void k_outer(const u16* __restrict__ Ab,
                                               const u16* __restrict__ kv,
                                               float* __restrict__ part) {
  __shared__ u16 At[2][64][40];
  __shared__ u16 Vt[2][128][40];
  int s = blockIdx.x, h = blockIdx.y, b = blockIdx.z;
  int tid = threadIdx.x;
  int w = tid >> 6, l = tid & 63;
  int adk = tid & 63, atq = tid >> 6;
  int vdv = tid & 127, vth = tid >> 7;
  int r = l & 15, q = l >> 4;
  f32x4 acc[8];
  #pragma unroll
  for (int n = 0; n < 8; ++n)
    #pragma unroll
    for (int j = 0; j < 4; ++j) acc[n][j] = 0.f;

  union { int4 v[2]; u16 u[16]; } vbuf;
  union { int4 v; u16 u[8]; } abuf;

  #define LOADT(KK) do {                                                              \
      int t0_ = s * 512 + (KK) * 32;                                                  \
      _Pragma("unroll")                                                               \
      for (int i = 0; i < 8; ++i)                                                     \
        abuf.u[i] = Ab[(size_t)(b * T_ + t0_ + atq * 8 + i) * HDK + h * DK_ + adk];   \
      _Pragma("unroll")                                                               \
      for (int i = 0; i < 16; ++i)                                                    \
        vbuf.u[i] = kv[(size_t)(b * T_ + t0_ + vth * 16 + i) * NN + HDK + h * DV_ + vdv]; \
    } while (0)

  #define WRITET(BF) do {                                                             \
      *(int4*)&At[BF][adk][atq * 8] = abuf.v;                                         \
      *(int4*)&Vt[BF][vdv][vth * 16] = vbuf.v[0];                                     \
      *(int4*)&Vt[BF][vdv][vth * 16 + 8] = vbuf.v[1];                                 \
    } while (0)

  LOADT(0);
  WRITET(0);
  for (int kk = 0; kk < 16; ++kk) {
    int cur = kk & 1;
    if (kk < 15) LOADT(kk + 1);
    __syncthreads();
    bf16x8 af = *(const bf16x8*)&At[cur][w * 16 + r][q * 8];
    #pragma unroll
    for (int n = 0; n < 8; ++n) {
      bf16x8 vf = *(const bf16x8*)&Vt[cur][n * 16 + r][q * 8];
      acc[n] = __builtin_amdgcn_mfma_f32_16x16x32_bf16(af, vf, acc[n], 0, 0, 0);
    }
    __syncthreads();
    if (kk < 15) WRITET(1 - cur);
  }
  #undef LOADT
  #undef WRITET

  float* dst = part + ((size_t)(b * H_ + h) * 8 + s) * (DK_ * DV_);
  #pragma unroll
  for (int n = 0; n < 8; ++n)
    #pragma unroll
    for (int j = 0; j < 4; ++j)
      dst[(w * 16 + q * 4 + j) * DV_ + n * 16 + r] = acc[n][j];
}

// K7: out = exp(g_total)*state + sum over 8 splits
__global__ __launch_bounds__(256) void k_final(const float* __restrict__ part,
                                               const float* __restrict__ gt,
                                               const float* __restrict__ st,
                                               float* __restrict__ out) {
  int i = blockIdx.x * 256 + threadIdx.x;
  int dv = i & 127, dk = (i >> 7) & 63, h = (i >> 13) & 15, b = i >> 17;
  size_t base = ((size_t)(b * H_ + h) * 8) * 8192 + dk * DV_ + dv;
  float s = 0.f;
  #pragma unroll
  for (int sp = 0; sp < 8; ++sp) s += part[base + (size_t)sp * 8192];
  float g = gt[b * HDK + h * DK_ + dk];
  out[i] = fexp(g) * st[i] + s;
}

extern "C" void kernel_launch(void* const* d_in, const int* in_sizes, int n_in,
                              void* d_out, int out_size, void* d_ws, size_t ws_size,
                              hipStream_t stream) {
  const float* hs = (const float*)d_in[0];
  const float* st = (const float*)d_in[1];
  const float* nw = (const float*)d_in[2];
  const float* kw = (const float*)d_in[3];
  const float* vw = (const float*)d_in[4];
  const float* w1 = (const float*)d_in[5];
  const float* w2 = (const float*)d_in[6];
  const float* gb = (const float*)d_in[7];
  float* out = (float*)d_out;
  char* ws = (char*)d_ws;

  u16*  Wb  = (u16*)(ws + 0);              // 12,582,912
  u16*  xb  = (u16*)(ws + 12582912);       // 67,108,864 (dead after gemm)
  float* y  = (float*)(ws + 79691776);     //  1,048,576
  u16*  kv  = (u16*)(ws + 80740352);       // 100,663,296
  u16*  gkh = (u16*)(ws + 181403648);      // 33,554,432 (f16)
  float* ct = (float*)(ws + 214958080);    //  1,048,576
  float* co = (float*)(ws + 216006656);    //  1,048,576
  float* gt = (float*)(ws + 217055232);    //     16,384
  u16*  Ab  = (u16*)(ws + 12582912);              // reuse xb region (33.5 MB)
  float* part = (float*)(ws + 12582912 + 33554432); // 16,777,216

  k_cvtw<<<dim3(3072), dim3(256), 0, stream>>>(kw, vw, Wb);
  k_rms<<<dim3(4096), dim3(256), 0, stream>>>(hs, nw, w1, xb, y);
  k_gemm<<<dim3(768), dim3(512), 0, stream>>>(xb, Wb, kv);
  k_gkcs<<<dim3(1024), dim3(256), 0, stream>>>(y, w2, gb, gkh, ct);
  k_scan<<<dim3(16), dim3(256), 0, stream>>>(ct, co, gt);
  k_decay<<<dim3(1024), dim3(256), 0, stream>>>(gkh, co, gt, kv, Ab);
  k_outer<<<dim3(8, 16, 4), dim3(256), 0, stream>>>(Ab, kv, part);
  k_final<<<dim3(2048), dim3(256), 0, stream>>>(part, gt, st, out);
}

// Round 11
// 364.670 us; speedup vs baseline: 6.2965x; 1.1656x over previous
//
#include <hip/hip_runtime.h>

#define B_ 4
#define T_ 4096
#define D_ 2048
#define H_ 16
#define DK_ 64
#define DV_ 128
#define HDK 1024
#define HDV 2048
#define NN 3072
#define MM 16384
#define NT_ 32  // D_/64 K-tiles (BK=64)

typedef unsigned short u16;
typedef unsigned int u32;
typedef __attribute__((ext_vector_type(8))) short bf16x8;
typedef __attribute__((ext_vector_type(4))) float f32x4;

typedef const __attribute__((address_space(1))) u16 gu16;
typedef __attribute__((address_space(3))) u16 lu16;

__device__ __forceinline__ float b2f(u16 u) {
  u32 x = ((u32)u) << 16; float f; __builtin_memcpy(&f, &x, 4); return f;
}
__device__ __forceinline__ u16 f2b(float f) {
  u32 x; __builtin_memcpy(&x, &f, 4);
  u32 r = x + 0x7FFFu + ((x >> 16) & 1u);
  return (u16)(r >> 16);
}
// fast logsig / exp via native v_exp_f32 / v_log_f32
__device__ __forceinline__ float fexp(float x) { return exp2f(x * 1.44269504f); }
__device__ __forceinline__ float flogsig(float z) {
  float u = exp2f(-fabsf(z) * 1.44269504f);
  float l = log2f(1.f + u) * 0.69314718f;
  return fminf(z, 0.f) - l;
}

// K1: convert [k_w; v_w] (3072 x 2048 f32) -> bf16
__global__ __launch_bounds__(256) void k_cvtw(const float* __restrict__ kw,
                                              const float* __restrict__ vw,
                                              u16* __restrict__ Wb) {
  int i = blockIdx.x * 256 + threadIdx.x;
  size_t e = (size_t)i * 8;
  const float* src = (e < (size_t)HDK * D_) ? (kw + e) : (vw + (e - (size_t)HDK * D_));
  float4 f0 = ((const float4*)src)[0];
  float4 f1 = ((const float4*)src)[1];
  union { int4 v; u16 u[8]; } o;
  o.u[0] = f2b(f0.x); o.u[1] = f2b(f0.y); o.u[2] = f2b(f0.z); o.u[3] = f2b(f0.w);
  o.u[4] = f2b(f1.x); o.u[5] = f2b(f1.y); o.u[6] = f2b(f1.z); o.u[7] = f2b(f1.w);
  *(int4*)(Wb + e) = o.v;
}

// K2: RMSNorm -> x (bf16), and y = x @ gk_w1^T (f32, 16 per row). 4 rows/block.
// (R3/R5-proven version — R9/R10's sharded variant measured ~60us SLOWER.)
__global__ __launch_bounds__(256) void k_rms(const float* __restrict__ hs,
                                             const float* __restrict__ nw,
                                             const float* __restrict__ w1,
                                             u16* __restrict__ xb,
                                             float* __restrict__ y) {
  int r0 = blockIdx.x * 4;
  int tid = threadIdx.x;
  int wv = tid >> 6, ln = tid & 63;
  __shared__ float red[4][4];
  __shared__ float ys[4][4][16];
  float x[4][8];
  float ssq[4];
  #pragma unroll
  for (int r = 0; r < 4; ++r) {
    const float4* hp = (const float4*)(hs + (size_t)(r0 + r) * D_);
    float4 a = hp[tid * 2], b = hp[tid * 2 + 1];
    x[r][0] = a.x; x[r][1] = a.y; x[r][2] = a.z; x[r][3] = a.w;
    x[r][4] = b.x; x[r][5] = b.y; x[r][6] = b.z; x[r][7] = b.w;
    float s = 0.f;
    #pragma unroll
    for (int i = 0; i < 8; ++i) s += x[r][i] * x[r][i];
    #pragma unroll
    for (int o = 32; o > 0; o >>= 1) s += __shfl_xor(s, o, 64);
    ssq[r] = s;
  }
  if (ln == 0) {
    #pragma unroll
    for (int r = 0; r < 4; ++r) red[wv][r] = ssq[r];
  }
  __syncthreads();
  const float4* np_ = (const float4*)nw;
  float4 n0 = np_[tid * 2], n1 = np_[tid * 2 + 1];
  float nwv[8] = {n0.x, n0.y, n0.z, n0.w, n1.x, n1.y, n1.z, n1.w};
  #pragma unroll
  for (int r = 0; r < 4; ++r) {
    float tot = red[0][r] + red[1][r] + red[2][r] + red[3][r];
    float inv = rsqrtf(tot * (1.f / D_) + 1e-5f);
    union { int4 v; u16 u[8]; } o;
    #pragma unroll
    for (int i = 0; i < 8; ++i) { x[r][i] = x[r][i] * inv * nwv[i]; o.u[i] = f2b(x[r][i]); }
    *(int4*)(xb + (size_t)(r0 + r) * D_ + tid * 8) = o.v;
  }
  float p[4][16];
  #pragma unroll
  for (int r = 0; r < 4; ++r)
    #pragma unroll
    for (int j = 0; j < 16; ++j) p[r][j] = 0.f;
  #pragma unroll
  for (int j = 0; j < 16; ++j) {
    const float4* wp = (const float4*)(w1 + (size_t)j * D_);
    float4 a = wp[tid * 2], b = wp[tid * 2 + 1];
    float wj[8] = {a.x, a.y, a.z, a.w, b.x, b.y, b.z, b.w};
    #pragma unroll
    for (int r = 0; r < 4; ++r) {
      float s = 0.f;
      #pragma unroll
      for (int i = 0; i < 8; ++i) s += x[r][i] * wj[i];
      p[r][j] = s;
    }
  }
  #pragma unroll
  for (int r = 0; r < 4; ++r)
    #pragma unroll
    for (int j = 0; j < 16; ++j) {
      float s = p[r][j];
      #pragma unroll
      for (int o = 32; o > 0; o >>= 1) s += __shfl_xor(s, o, 64);
      p[r][j] = s;
    }
  if (ln == 0) {
    for (int r = 0; r < 4; ++r)
      for (int j = 0; j < 16; ++j) ys[wv][r][j] = p[r][j];
  }
  __syncthreads();
  if (tid < 64) {
    int r = tid >> 4, j = tid & 15;
    y[(size_t)(r0 + r) * 16 + j] = ys[0][r][j] + ys[1][r][j] + ys[2][r][j] + ys[3][r][j];
  }
}

// K3: kv = x @ Wb^T. 256x256 tile, 8 waves, BK=64, 2 dbuf x 2 k-half LDS
// (R7-proven staging: wave-uniform GLDS dest, pre-swizzled source cols).
// 4 phases of 16 MFMA per K-tile with fine ds_read/stage interleave;
// 2 sync points per tile (vmcnt(2)@P0, vmcnt(4)@P2), lgkmcnt(0)+sched_barrier
// before every MFMA cluster (rule #18). [R8-measured: 365.3us total]
#define GLDS(SRC, DST) __builtin_amdgcn_global_load_lds((gu16*)(SRC), (lu16*)(DST), 16, 0, 0)

#define MFMA16(AF, MB) do {                                                    \
    __builtin_amdgcn_s_setprio(1);                                             \
    _Pragma("unroll")                                                          \
    for (int mi_ = 0; mi_ < 4; ++mi_)                                          \
      _Pragma("unroll")                                                        \
      for (int ni_ = 0; ni_ < 4; ++ni_)                                        \
        acc[(MB) + mi_][ni_] = __builtin_amdgcn_mfma_f32_16x16x32_bf16(        \
            AF[mi_], bf[ni_], acc[(MB) + mi_][ni_], 0, 0, 0);                  \
    __builtin_amdgcn_s_setprio(0);                                             \
    __builtin_amdgcn_sched_barrier(0);                                         \
  } while (0)

#define KTILE(DB, NB, VM0, VM2, ST) do {                                       \
    /* P0: sync, read kh0 frags (a0-3,b0-3), stage A-kh0', MFMA mi0-3 */       \
    asm volatile("s_waitcnt vmcnt(" VM0 ")" ::: "memory");                     \
    __builtin_amdgcn_s_barrier();                                              \
    __builtin_amdgcn_sched_barrier(0);                                         \
    _Pragma("unroll")                                                          \
    for (int mi_ = 0; mi_ < 4; ++mi_)                                          \
      af[mi_] = *(const bf16x8*)&SA[DB][0][(wr * 128 + mi_ * 16 + r) * 32 + kcol]; \
    _Pragma("unroll")                                                          \
    for (int ni_ = 0; ni_ < 4; ++ni_)                                          \
      bf[ni_] = *(const bf16x8*)&SB[DB][0][(wc * 64 + ni_ * 16 + r) * 32 + kcol]; \
    if (ST) { GLDS(An, &SA[NB][0][lw]); GLDS(An + 16 * D_, &SA[NB][0][lw + 512]); } \
    asm volatile("s_waitcnt lgkmcnt(0)" ::: "memory");                         \
    __builtin_amdgcn_sched_barrier(0);                                         \
    MFMA16(af, 0);                                                             \
    /* P1: read a4-7(kh0), stage A-kh1', MFMA mi4-7 (b reused) */              \
    _Pragma("unroll")                                                          \
    for (int mi_ = 0; mi_ < 4; ++mi_)                                          \
      af2[mi_] = *(const bf16x8*)&SA[DB][0][(wr * 128 + (4 + mi_) * 16 + r) * 32 + kcol]; \
    if (ST) { GLDS(An + 32, &SA[NB][1][lw]); GLDS(An + 32 + 16 * D_, &SA[NB][1][lw + 512]); } \
    asm volatile("s_waitcnt lgkmcnt(0)" ::: "memory");                         \
    __builtin_amdgcn_sched_barrier(0);                                         \
    MFMA16(af2, 4);                                                            \
    /* P2: sync, read kh1 frags, stage B-kh0', MFMA mi0-3 */                   \
    asm volatile("s_waitcnt vmcnt(" VM2 ")" ::: "memory");                     \
    __builtin_amdgcn_s_barrier();                                              \
    __builtin_amdgcn_sched_barrier(0);                                         \
    _Pragma("unroll")                                                          \
    for (int mi_ = 0; mi_ < 4; ++mi_)                                          \
      af[mi_] = *(const bf16x8*)&SA[DB][1][(wr * 128 + mi_ * 16 + r) * 32 + kcol]; \
    _Pragma("unroll")                                                          \
    for (int ni_ = 0; ni_ < 4; ++ni_)                                          \
      bf[ni_] = *(const bf16x8*)&SB[DB][1][(wc * 64 + ni_ * 16 + r) * 32 + kcol]; \
    if (ST) { GLDS(Bn, &SB[NB][0][lw]); GLDS(Bn + 16 * D_, &SB[NB][0][lw + 512]); } \
    asm volatile("s_waitcnt lgkmcnt(0)" ::: "memory");                         \
    __builtin_amdgcn_sched_barrier(0);                                         \
    MFMA16(af, 0);                                                             \
    /* P3: read a4-7(kh1), stage B-kh1', MFMA mi4-7 */                         \
    _Pragma("unroll")                                                          \
    for (int mi_ = 0; mi_ < 4; ++mi_)                                          \
      af2[mi_] = *(const bf16x8*)&SA[DB][1][(wr * 128 + (4 + mi_) * 16 + r) * 32 + kcol]; \
    if (ST) { GLDS(Bn + 32, &SB[NB][1][lw]); GLDS(Bn + 32 + 16 * D_, &SB[NB][1][lw + 512]); } \
    asm volatile("s_waitcnt lgkmcnt(0)" ::: "memory");                         \
    __builtin_amdgcn_sched_barrier(0);                                         \
    MFMA16(af2, 4);                                                            \
  } while (0)

__global__ __launch_bounds__(512, 2) void k_gemm(const u16* __restrict__ X,
                                                 const u16* __restrict__ W,
                                                 u16* __restrict__ C) {
  __shared__ u16 SA[2][2][8192];  // [dbuf][k-half][256 rows x 32 cols]
  __shared__ u16 SB[2][2][8192];
  int bid = blockIdx.x;
  int swzb = (bid & 7) * 96 + (bid >> 3);   // bijective XCD swizzle (768%8==0)
  int tm = swzb / 12, tn = swzb - tm * 12;
  int m0 = tm << 8, n0 = tn << 8;
  int tid = threadIdx.x;
  int w = tid >> 6, l = tid & 63;
  int wr = w >> 2, wc = w & 3;
  // staging coords (wave-uniform LDS base; per-lane global src) — R7-proven
  int arow = w * 32 + (l >> 2);
  int csw = 8 * ((l & 3) ^ ((l >> 3) & 3));   // pre-swizzled source col
  const u16* Ag = X + (size_t)(m0 + arow) * D_ + csw;
  const u16* Bg = W + (size_t)(n0 + arow) * D_ + csw;
  int lw = w * 1024;                           // u16 offset of wave's chunk pair
  // fragment read coords
  int r = l & 15, kq = l >> 4;
  int kcol = 8 * (kq ^ ((r >> 1) & 3));

  f32x4 acc[8][4];
  #pragma unroll
  for (int mi = 0; mi < 8; ++mi)
    #pragma unroll
    for (int ni = 0; ni < 4; ++ni)
      #pragma unroll
      for (int q = 0; q < 4; ++q) acc[mi][ni][q] = 0.f;

  bf16x8 af[4], af2[4], bf[4];

  // prologue: tile 0 in FIFO order A-kh0, A-kh1, B-kh0, B-kh1
  GLDS(Ag,           &SA[0][0][lw]);  GLDS(Ag + 16 * D_,      &SA[0][0][lw + 512]);
  GLDS(Ag + 32,      &SA[0][1][lw]);  GLDS(Ag + 32 + 16 * D_, &SA[0][1][lw + 512]);
  GLDS(Bg,           &SB[0][0][lw]);  GLDS(Bg + 16 * D_,      &SB[0][0][lw + 512]);
  GLDS(Bg + 32,      &SB[0][1][lw]);  GLDS(Bg + 32 + 16 * D_, &SB[0][1][lw + 512]);

  for (int kt = 0; kt < NT_ - 1; ++kt) {
    int db = kt & 1, nb = db ^ 1;
    const u16* An = Ag + (size_t)(kt + 1) * 64;
    const u16* Bn = Bg + (size_t)(kt + 1) * 64;
    KTILE(db, nb, "2", "4", 1);
  }
  {
    const u16* An = Ag;  // unused (ST=0)
    const u16* Bn = Bg;
    KTILE(1, 0, "2", "0", 0);
  }

  int cr = (l >> 4) * 4, cc = l & 15;
  #pragma unroll
  for (int mi = 0; mi < 8; ++mi)
    #pragma unroll
    for (int ni = 0; ni < 4; ++ni)
      #pragma unroll
      for (int q = 0; q < 4; ++q) {
        int gm = m0 + wr * 128 + mi * 16 + cr + q;
        int gn = n0 + wc * 64 + ni * 16 + cc;
        C[(size_t)gm * NN + gn] = f2b(acc[mi][ni][q]);
      }
}

// K4: fused gk + chunk-sum, 64-t chunks, grid 1024. gk stored f16;
// ct accumulated from the f16-ROUNDED values (bit-consistent with k_decay).
__global__ __launch_bounds__(256) void k_gkcs(const float* __restrict__ y,
                                              const float* __restrict__ w2,
                                              const float* __restrict__ gb,
                                              u16* __restrict__ gkh,
                                              float* __restrict__ ct) {
  __shared__ float yl[64][16];
  int blk = blockIdx.x;
  int cg = blk & 3, tc = (blk >> 2) & 63, b = blk >> 8;
  int tid = threadIdx.x;
  int c = cg * 256 + tid;
  {
    int row = tid >> 2, q = tid & 3;
    const float4* src = (const float4*)(y + (size_t)(b * T_ + tc * 64 + row) * 16 + q * 4);
    *(float4*)&yl[row][q * 4] = *src;
  }
  float w2r[16];
  {
    const float4* wsrc = (const float4*)(w2 + (size_t)c * 16);
    float4 q0 = wsrc[0], q1 = wsrc[1], q2 = wsrc[2], q3 = wsrc[3];
    w2r[0] = q0.x; w2r[1] = q0.y; w2r[2] = q0.z; w2r[3] = q0.w;
    w2r[4] = q1.x; w2r[5] = q1.y; w2r[6] = q1.z; w2r[7] = q1.w;
    w2r[8] = q2.x; w2r[9] = q2.y; w2r[10] = q2.z; w2r[11] = q2.w;
    w2r[12] = q3.x; w2r[13] = q3.y; w2r[14] = q3.z; w2r[15] = q3.w;
  }
  float gbr = gb[c];
  __syncthreads();
  float sum = 0.f;
  size_t rowbase = (size_t)(b * T_ + tc * 64) * HDK + c;
  for (int t = 0; t < 64; ++t) {
    const float4* yv4 = (const float4*)&yl[t][0];
    float4 y0 = yv4[0], y1 = yv4[1], y2 = yv4[2], y3 = yv4[3];
    float z = gbr;
    z = fmaf(y0.x, w2r[0], z);  z = fmaf(y0.y, w2r[1], z);
    z = fmaf(y0.z, w2r[2], z);  z = fmaf(y0.w, w2r[3], z);
    z = fmaf(y1.x, w2r[4], z);  z = fmaf(y1.y, w2r[5], z);
    z = fmaf(y1.z, w2r[6], z);  z = fmaf(y1.w, w2r[7], z);
    z = fmaf(y2.x, w2r[8], z);  z = fmaf(y2.y, w2r[9], z);
    z = fmaf(y2.z, w2r[10], z); z = fmaf(y2.w, w2r[11], z);
    z = fmaf(y3.x, w2r[12], z); z = fmaf(y3.y, w2r[13], z);
    z = fmaf(y3.z, w2r[14], z); z = fmaf(y3.w, w2r[15], z);
    float g = flogsig(z) * (1.f / 16.f);
    _Float16 hv = (_Float16)g;
    u16 bits; __builtin_memcpy(&bits, &hv, 2);
    gkh[rowbase + (size_t)t * HDK] = bits;
    sum += (float)hv;
  }
  ct[(size_t)(b * 64 + tc) * HDK + c] = sum;
}

// E2: scan 64 chunk sums -> exclusive offsets + totals. grid 16 (b x cg).
__global__ __launch_bounds__(256) void k_scan(const float* __restrict__ ct,
                                              float* __restrict__ co,
                                              float* __restrict__ gt) {
  int b = blockIdx.x >> 2, cg = blockIdx.x & 3;
  int c = cg * 256 + threadIdx.x;
  float run = 0.f;
  #pragma unroll 8
  for (int tc = 0; tc < 64; ++tc) {
    size_t idx = (size_t)(b * 64 + tc) * HDK + c;
    co[idx] = run;
    run += ct[idx];
  }
  gt[b * HDK + c] = run;
}

// E3: A = k * exp(g_total - G) (bf16). 64-t chunks, grid 1024.
__global__ __launch_bounds__(256) void k_decay(const u16* __restrict__ gkh,
                                               const float* __restrict__ co,
                                               const float* __restrict__ gt,
                                               const u16* __restrict__ kv,
                                               u16* __restrict__ Ab) {
  int blk = blockIdx.x;
  int cg = blk & 3, tc = (blk >> 2) & 63, b = blk >> 8;
  int c = cg * 256 + threadIdx.x;
  float run = co[(size_t)(b * 64 + tc) * HDK + c];
  float g = gt[b * HDK + c];
  #pragma unroll 8
  for (int tt = 0; tt < 64; ++tt) {
    size_t row = (size_t)(b * T_) + tc * 64 + tt;
    u16 bits = gkh[row * HDK + c];
    _Float16 hv; __builtin_memcpy(&hv, &bits, 2);
    run += (float)hv;
    float decay = fexp(g - run);
    float kvl = b2f(kv[row * NN + c]);
    Ab[row * HDK + c] = f2b(kvl * decay);
  }
}

// K6: MFMA outer product. block = (s, h, b); 8 splits x 512 t; K-steps of 32 t.
__global__ __launch_bounds__(256) void k_outer(const u16* __restrict__ Ab,
                                               const u16* __restrict__ kv,
                                               float* __restrict__ part) {
  __shared__ u16 At[2][64][40];
  __shared__ u16 Vt[2][128][40];
  int s = blockIdx.x, h = blockIdx.y, b = blockIdx.z;
  int tid = threadIdx.x;
  int w = tid >> 6, l = tid & 63;
  int adk = tid & 63, atq = tid >> 6;
  int vdv = tid & 127, vth = tid >> 7;
  int r = l & 15, q = l >> 4;
  f32x4 acc[8];
  #pragma unroll
  for (int n = 0; n < 8; ++n)
    #pragma unroll
    for (int j = 0; j < 4; ++j) acc[n][j] = 0.f;

  union { int4 v[2]; u16 u[16]; } vbuf;
  union { int4 v; u16 u[8]; } abuf;

  #define LOADT(KK) do {                                                              \
      int t0_ = s * 512 + (KK) * 32;                                                  \
      _Pragma("unroll")                                                               \
      for (int i = 0; i < 8; ++i)                                                     \
        abuf.u[i] = Ab[(size_t)(b * T_ + t0_ + atq * 8 + i) * HDK + h * DK_ + adk];   \
      _Pragma("unroll")                                                               \
      for (int i = 0; i < 16; ++i)                                                    \
        vbuf.u[i] = kv[(size_t)(b * T_ + t0_ + vth * 16 + i) * NN + HDK + h * DV_ + vdv]; \
    } while (0)

  #define WRITET(BF) do {                                                             \
      *(int4*)&At[BF][adk][atq * 8] = abuf.v;                                         \
      *(int4*)&Vt[BF][vdv][vth * 16] = vbuf.v[0];                                     \
      *(int4*)&Vt[BF][vdv][vth * 16 + 8] = vbuf.v[1];                                 \
    } while (0)

  LOADT(0);
  WRITET(0);
  for (int kk = 0; kk < 16; ++kk) {
    int cur = kk & 1;
    if (kk < 15) LOADT(kk + 1);
    __syncthreads();
    bf16x8 af = *(const bf16x8*)&At[cur][w * 16 + r][q * 8];
    #pragma unroll
    for (int n = 0; n < 8; ++n) {
      bf16x8 vf = *(const bf16x8*)&Vt[cur][n * 16 + r][q * 8];
      acc[n] = __builtin_amdgcn_mfma_f32_16x16x32_bf16(af, vf, acc[n], 0, 0, 0);
    }
    __syncthreads();
    if (kk < 15) WRITET(1 - cur);
  }
  #undef LOADT
  #undef WRITET

  float* dst = part + ((size_t)(b * H_ + h) * 8 + s) * (DK_ * DV_);
  #pragma unroll
  for (int n = 0; n < 8; ++n)
    #pragma unroll
    for (int j = 0; j < 4; ++j)
      dst[(w * 16 + q * 4 + j) * DV_ + n * 16 + r] = acc[n][j];
}

// K7: out = exp(g_total)*state + sum over 8 splits
__global__ __launch_bounds__(256) void k_final(const float* __restrict__ part,
                                               const float* __restrict__ gt,
                                               const float* __restrict__ st,
                                               float* __restrict__ out) {
  int i = blockIdx.x * 256 + threadIdx.x;
  int dv = i & 127, dk = (i >> 7) & 63, h = (i >> 13) & 15, b = i >> 17;
  size_t base = ((size_t)(b * H_ + h) * 8) * 8192 + dk * DV_ + dv;
  float s = 0.f;
  #pragma unroll
  for (int sp = 0; sp < 8; ++sp) s += part[base + (size_t)sp * 8192];
  float g = gt[b * HDK + h * DK_ + dk];
  out[i] = fexp(g) * st[i] + s;
}

extern "C" void kernel_launch(void* const* d_in, const int* in_sizes, int n_in,
                              void* d_out, int out_size, void* d_ws, size_t ws_size,
                              hipStream_t stream) {
  const float* hs = (const float*)d_in[0];
  const float* st = (const float*)d_in[1];
  const float* nw = (const float*)d_in[2];
  const float* kw = (const float*)d_in[3];
  const float* vw = (const float*)d_in[4];
  const float* w1 = (const float*)d_in[5];
  const float* w2 = (const float*)d_in[6];
  const float* gb = (const float*)d_in[7];
  float* out = (float*)d_out;
  char* ws = (char*)d_ws;

  u16*  Wb  = (u16*)(ws + 0);              // 12,582,912
  u16*  xb  = (u16*)(ws + 12582912);       // 67,108,864 (dead after gemm)
  float* y  = (float*)(ws + 79691776);     //  1,048,576
  u16*  kv  = (u16*)(ws + 80740352);       // 100,663,296
  u16*  gkh = (u16*)(ws + 181403648);      // 33,554,432 (f16)
  float* ct = (float*)(ws + 214958080);    //  1,048,576
  float* co = (float*)(ws + 216006656);    //  1,048,576
  float* gt = (float*)(ws + 217055232);    //     16,384
  u16*  Ab  = (u16*)(ws + 12582912);              // reuse xb region (33.5 MB)
  float* part = (float*)(ws + 12582912 + 33554432); // 16,777,216

  k_cvtw<<<dim3(3072), dim3(256), 0, stream>>>(kw, vw, Wb);
  k_rms<<<dim3(4096), dim3(256), 0, stream>>>(hs, nw, w1, xb, y);
  k_gemm<<<dim3(768), dim3(512), 0, stream>>>(xb, Wb, kv);
  k_gkcs<<<dim3(1024), dim3(256), 0, stream>>>(y, w2, gb, gkh, ct);
  k_scan<<<dim3(16), dim3(256), 0, stream>>>(ct, co, gt);
  k_decay<<<dim3(1024), dim3(256), 0, stream>>>(gkh, co, gt, kv, Ab);
  k_outer<<<dim3(8, 16, 4), dim3(256), 0, stream>>>(Ab, kv, part);
  k_final<<<dim3(2048), dim3(256), 0, stream>>>(part, gt, st, out);
}